// Round 9
// baseline (2189.199 us; speedup 1.0000x reference)
//
#include <hip/hip_runtime.h>

typedef float f32x4 __attribute__((ext_vector_type(4)));
typedef int   i32x4 __attribute__((ext_vector_type(4)));
typedef unsigned int u32;
typedef unsigned long long u64;

#define TN 2048
// LDS byte offsets
#define W1B 0u        // [129][256] f32 (row 128 = zeros)      132096 B
#define W2B 132096u   // [65][16][4] f32 (group 64 = zeros)     16640 B
#define XB  148736u   // [2064] f32 (i <-> x[i-3], zero pad)     8256 B
#define R2B 156992u   // [66] 16B records (L2 c-lists)           1056 B
#define R3B 158048u   // [66] 16B records (L3 (l,sub)-lists)     1056 B
#define MBB 159104u   // [64] 16B L1 mask records                1024 B
#define HBB 160128u   // [64] 32B L2-spike ballot records        2048 B
// total 162176 B  (< 160 KiB = 163840)

// ---------------- prep: repack weights into d_ws ----------------
__global__ __launch_bounds__(256)
void prep_kernel(const float* __restrict__ w1, const float* __restrict__ w2,
                 float* __restrict__ w1T, float* __restrict__ w2Q) {
    int bid = blockIdx.x;
    if (bid < 32) {
        __shared__ float tile[32][33];
        int h0 = (bid >> 2) << 5, c0 = (bid & 3) << 5;
        int tx = threadIdx.x & 31, ty = threadIdx.x >> 5;
        #pragma unroll
        for (int i = ty; i < 32; i += 8) tile[i][tx] = w1[(h0 + i) * 128 + (c0 + tx)];
        __syncthreads();
        #pragma unroll
        for (int i = ty; i < 32; i += 8) w1T[(c0 + i) * 256 + (h0 + tx)] = tile[tx][i];
    } else {
        for (int idx = threadIdx.x; idx < 65 * 64; idx += 256) {
            int l = idx >> 6, n = (idx >> 2) & 15, j = idx & 3;
            w2Q[idx] = (l < 64 && n < 10) ? w2[n * 256 + 4 * l + j] : 0.0f;
        }
    }
}

// ---- asm helpers ----
__device__ __forceinline__ void ds_load4(f32x4& d, unsigned addr) {
    asm volatile("ds_read_b128 %0, %1" : "=&v"(d) : "v"(addr));
}
__device__ __forceinline__ void ds_load4i(i32x4& d, unsigned addr) {
    asm volatile("ds_read_b128 %0, %1" : "=&v"(d) : "v"(addr));
}
__device__ __forceinline__ void ds_write4i(unsigned addr, i32x4 v) {
    asm volatile("ds_write_b128 %0, %1" :: "v"(addr), "v"(v) : "memory");
}
__device__ __forceinline__ void ds_issue2(f32x4& r0, f32x4& r1, unsigned a0, unsigned a1) {
    asm volatile("ds_read_b128 %0, %2\n\t"
                 "ds_read_b128 %1, %3"
                 : "=&v"(r0), "=&v"(r1) : "v"(a0), "v"(a1));
}
__device__ __forceinline__ void ds_issue8(
        f32x4& r0, f32x4& r1, f32x4& r2, f32x4& r3,
        f32x4& r4, f32x4& r5, f32x4& r6, f32x4& r7,
        unsigned a0, unsigned a1, unsigned a2, unsigned a3,
        unsigned a4, unsigned a5, unsigned a6, unsigned a7) {
    asm volatile("ds_read_b128 %0, %8\n\t"
                 "ds_read_b128 %1, %9\n\t"
                 "ds_read_b128 %2, %10\n\t"
                 "ds_read_b128 %3, %11\n\t"
                 "ds_read_b128 %4, %12\n\t"
                 "ds_read_b128 %5, %13\n\t"
                 "ds_read_b128 %6, %14\n\t"
                 "ds_read_b128 %7, %15"
                 : "=&v"(r0), "=&v"(r1), "=&v"(r2), "=&v"(r3),
                   "=&v"(r4), "=&v"(r5), "=&v"(r6), "=&v"(r7)
                 : "v"(a0), "v"(a1), "v"(a2), "v"(a3),
                   "v"(a4), "v"(a5), "v"(a6), "v"(a7));
}
#define WAIT0 do { asm volatile("s_waitcnt lgkmcnt(0)" ::: "memory"); \
                   __builtin_amdgcn_sched_barrier(0); } while (0)

// ascending-index pop from 128-bit (lo,hi); pad 128 (not hit under loop guard)
__device__ __forceinline__ int pop_next(u64& lo, u64& hi) {
    bool hl = lo != 0ull, hh = hi != 0ull, have = hl || hh;
    u64 sel  = hl ? lo : hi;
    u64 selg = have ? sel : 1ull;
    int c = __builtin_ctzll(selg) + (hl ? 0 : 64);
    c = have ? c : 128;
    u64 cl = selg & (selg - 1ull);
    lo = hl ? cl : lo;
    hi = (hl || !hh) ? hi : cl;
    return c;
}

// ---- P1: one IF1 step; masks parked into LDS record (lane 0 writes) ----
template<int OFF>
__device__ __forceinline__ void p1_step(int lane, unsigned mrec, const float (&xw)[12],
        const float (&cwa)[7], const float (&cwb)[7],
        float& v1a, float& v1b) {
    float xca = 0.f, xcb = 0.f;
    #pragma unroll
    for (int k = 0; k < 7; ++k) {
        float xv = xw[OFF + k];
        xca = fmaf(xv, cwa[k], xca);
        xcb = fmaf(xv, cwb[k], xcb);
    }
    float na = v1a + xca, nb = v1b + xcb;
    bool sa = na >= 1.0f, sb = nb >= 1.0f;
    u64 ma = __ballot(sa), mb = __ballot(sb);
    v1a = sa ? 0.f : na;
    v1b = sb ? 0.f : nb;
    if (lane == 0) {
        i32x4 rec = { (int)(u32)ma, (int)(u32)(ma >> 32),
                      (int)(u32)mb, (int)(u32)(mb >> 32) };
        ds_write4i(mrec, rec);
    }
}

// ---- P2 helpers ----
__device__ __forceinline__ void issue8_from(i32x4 R, unsigned w1a,
        f32x4& g0, f32x4& g1, f32x4& g2, f32x4& g3,
        f32x4& g4, f32x4& g5, f32x4& g6, f32x4& g7) {
    u32 r0 = (u32)R[0], r1 = (u32)R[1], r2 = (u32)R[2];
    u32 c0 = (r0 >> 8) & 0xFFu, c1 = (r0 >> 16) & 0xFFu, c2 = r0 >> 24;
    u32 c3 = r1 & 0xFFu, c4 = (r1 >> 8) & 0xFFu, c5 = (r1 >> 16) & 0xFFu, c6 = r1 >> 24;
    u32 c7 = r2 & 0xFFu;
    ds_issue8(g0, g1, g2, g3, g4, g5, g6, g7,
              w1a + (c0 << 10), w1a + (c1 << 10), w1a + (c2 << 10), w1a + (c3 << 10),
              w1a + (c4 << 10), w1a + (c5 << 10), w1a + (c6 << 10), w1a + (c7 << 10));
}

__device__ __forceinline__ void consume2(
        f32x4 g0, f32x4 g1, f32x4 g2, f32x4 g3,
        f32x4 g4, f32x4 g5, f32x4 g6, f32x4 g7,
        i32x4 R, int t, int lane, unsigned w1a, unsigned mbu, unsigned hbu,
        float& v20, float& v21, float& v22, float& v23) {
    int cnt = (int)((u32)R[0] & 0xFFu);
    f32x4 inc = g0;
    inc += g1; inc += g2; inc += g3; inc += g4; inc += g5; inc += g6; inc += g7;
    if (__builtin_expect(cnt > 8, 0)) {
        u32 r2 = (u32)R[2], r3 = (u32)R[3];
        #define EX2(s, cexpr) if ((s) < cnt) { u32 c = (cexpr) & 0xFFu; \
            f32x4 tv; ds_load4(tv, w1a + (c << 10)); WAIT0; inc += tv; }
        EX2(8,  r2 >> 8)  EX2(9,  r2 >> 16) EX2(10, r2 >> 24)
        EX2(11, r3)       EX2(12, r3 >> 8)  EX2(13, r3 >> 16) EX2(14, r3 >> 24)
        #undef EX2
        if (__builtin_expect(cnt > 15, 0)) {
            i32x4 M; ds_load4i(M, mbu + ((u32)t << 4)); WAIT0;
            u64 lo = ((u64)(u32)M[1] << 32) | (u32)M[0];
            u64 hi = ((u64)(u32)M[3] << 32) | (u32)M[2];
            int skip = 15;
            while (lo | hi) {
                int c = pop_next(lo, hi);
                if (skip > 0) { --skip; }
                else { f32x4 tv; ds_load4(tv, w1a + ((u32)c << 10)); WAIT0; inc += tv; }
            }
        }
    }
    float n0 = v20 + inc[0], n1 = v21 + inc[1], n2 = v22 + inc[2], n3 = v23 + inc[3];
    bool s0 = n0 >= 1.0f, s1 = n1 >= 1.0f, s2 = n2 >= 1.0f, s3 = n3 >= 1.0f;
    u64 b0 = __ballot(s0), b1 = __ballot(s1), b2 = __ballot(s2), b3 = __ballot(s3);
    v20 = s0 ? 0.f : n0; v21 = s1 ? 0.f : n1;
    v22 = s2 ? 0.f : n2; v23 = s3 ? 0.f : n3;
    if (lane == 0) {
        i32x4 ra = { (int)(u32)b0, (int)(u32)(b0 >> 32),
                     (int)(u32)b1, (int)(u32)(b1 >> 32) };
        i32x4 rb = { (int)(u32)b2, (int)(u32)(b2 >> 32),
                     (int)(u32)b3, (int)(u32)(b3 >> 32) };
        unsigned ha = hbu + ((u32)t << 5);
        ds_write4i(ha, ra);
        ds_write4i(ha + 16u, rb);
    }
}

// ---- P3 helpers ----
__device__ __forceinline__ void issue2_from(i32x4 R, unsigned w2a, f32x4& q0, f32x4& q1) {
    u32 r0 = (u32)R[0];
    u32 l0 = (r0 >> 8) & 0xFFu, l1 = r0 >> 24;
    ds_issue2(q0, q1, w2a + (l0 << 8), w2a + (l1 << 8));
}

__device__ __forceinline__ void gated4(float& inc3, u32 sub, f32x4 q) {
    inc3 = fmaf((sub & 1u) ? 1.0f : 0.0f, q[0], inc3);
    inc3 = fmaf((sub & 2u) ? 1.0f : 0.0f, q[1], inc3);
    inc3 = fmaf((sub & 4u) ? 1.0f : 0.0f, q[2], inc3);
    inc3 = fmaf((sub & 8u) ? 1.0f : 0.0f, q[3], inc3);
}

__device__ __forceinline__ void consume3(f32x4 q0, f32x4 q1, i32x4 R, int t,
        unsigned w2a, unsigned hbu, float& v3, float& acc) {
    u32 r0 = (u32)R[0], r1 = (u32)R[1];
    int cnt = (int)(r0 & 0xFFu);
    u32 sub0 = (r0 >> 16) & 0xFFu, sub1 = r1 & 0xFFu;
    float inc3 = 0.f;
    gated4(inc3, sub0, q0);
    gated4(inc3, sub1, q1);
    if (__builtin_expect(cnt > 2, 0)) {
        u32 r2 = (u32)R[2], r3 = (u32)R[3];
        #define EX3(k, lexpr, sexpr) if ((k) < cnt && (k) < 7) { \
            u32 l = (lexpr) & 0xFFu, sb = (sexpr) & 0xFFu; \
            f32x4 qv; ds_load4(qv, w2a + (l << 8)); WAIT0; gated4(inc3, sb, qv); }
        EX3(2, r1 >> 8,  r1 >> 16)
        EX3(3, r1 >> 24, r2)
        EX3(4, r2 >> 8,  r2 >> 16)
        EX3(5, r2 >> 24, r3)
        EX3(6, r3 >> 8,  r3 >> 16)
        #undef EX3
        if (__builtin_expect(cnt > 7, 0)) {
            unsigned ha = hbu + ((u32)t << 5);
            i32x4 HA, HB;
            ds_load4i(HA, ha); ds_load4i(HB, ha + 16u); WAIT0;
            u64 h0 = ((u64)(u32)HA[1] << 32) | (u32)HA[0];
            u64 h1 = ((u64)(u32)HA[3] << 32) | (u32)HA[2];
            u64 h2 = ((u64)(u32)HB[1] << 32) | (u32)HB[0];
            u64 h3 = ((u64)(u32)HB[3] << 32) | (u32)HB[2];
            u64 gm = h0 | h1 | h2 | h3;
            int skip = 7;
            while (gm) {
                int l = __builtin_ctzll(gm); gm &= gm - 1ull;
                if (skip > 0) { --skip; continue; }
                u32 sb = (u32)((h0 >> l) & 1ull) | ((u32)((h1 >> l) & 1ull) << 1)
                       | ((u32)((h2 >> l) & 1ull) << 2) | ((u32)((h3 >> l) & 1ull) << 3);
                f32x4 qv; ds_load4(qv, w2a + ((u32)l << 8)); WAIT0;
                gated4(inc3, sb, qv);
            }
        }
    }
    float nn = v3 + inc3;
    bool ss = nn >= 1.0f;
    v3 = ss ? 0.f : nn;
    acc += ss ? 1.0f : 0.0f;
}

// ---------------- main: one wave per batch, phased 64-step chunks ----------------
__global__ __launch_bounds__(256, 1)
void snn_main(const float* __restrict__ x,
              const float* __restrict__ convw,
              const float* __restrict__ w1Tg,
              const float* __restrict__ w2Qg,
              float* __restrict__ out) {
    extern __shared__ float lds[];
    const int b = blockIdx.x;
    const int tid = threadIdx.x;

    {   // stage: w1T (+ zero row), w2Q (+ zero group), x, pad records
        const float4* s4 = (const float4*)w1Tg;
        float4* d4 = (float4*)lds;
        for (int i = tid; i < 8192; i += 256) d4[i] = s4[i];
        if (tid < 64) d4[8192 + tid] = make_float4(0.f, 0.f, 0.f, 0.f);
        const float4* s2 = (const float4*)w2Qg;
        float4* d2 = (float4*)(lds + W2B / 4);
        for (int i = tid; i < 1040; i += 256) d2[i] = s2[i];
        float* xLs = lds + XB / 4;
        for (int i = tid; i < 2064; i += 256) {
            int l = i - 3;
            xLs[i] = (l >= 0 && l < TN) ? x[b * TN + l] : 0.0f;
        }
        if (tid == 64) {   // REC2 pads: cnt=0, c=128 -> zero row
            i32x4 pr = { (int)0x80808000, (int)0x80808080, (int)0x80808080, (int)0x80808080 };
            *(i32x4*)((char*)lds + R2B + 64 * 16) = pr;
            *(i32x4*)((char*)lds + R2B + 65 * 16) = pr;
        }
        if (tid == 65) {   // REC3 pads: l=64 zero group, sub=0, cnt=0
            i32x4 p3 = { 0x40004000, 0x40004000, 0x40004000, 0x00004000 };
            *(i32x4*)((char*)lds + R3B + 64 * 16) = p3;
            *(i32x4*)((char*)lds + R3B + 65 * 16) = p3;
        }
    }
    __syncthreads();
    if (tid >= 64) return;
    const int lane = tid;

    const unsigned ldsbase = (unsigned)(uintptr_t)(void*)lds;
    const unsigned w1a  = ldsbase + W1B + (unsigned)lane * 16u;          // + (c<<10)
    const unsigned w2a  = ldsbase + W2B + (unsigned)(lane & 15) * 16u;   // + (l<<8)
    const unsigned r2u  = ldsbase + R2B;                                 // uniform reads
    const unsigned r3u  = ldsbase + R3B;
    const unsigned r2w  = r2u + (unsigned)lane * 16u;                    // per-lane writes
    const unsigned r3w  = r3u + (unsigned)lane * 16u;
    const unsigned mbu  = ldsbase + MBB;                                 // mask records
    const unsigned hbu  = ldsbase + HBB;                                 // H-ballot records
    const unsigned mrd  = mbu + (unsigned)lane * 16u;                    // lane's mask rec
    const unsigned hrd  = hbu + (unsigned)lane * 32u;                    // lane's H rec

    float cwa[7], cwb[7];
    #pragma unroll
    for (int k = 0; k < 7; ++k) {
        cwa[k] = convw[lane * 7 + k];
        cwb[k] = convw[(lane + 64) * 7 + k];
    }

    float v1a = 0.f, v1b = 0.f;
    float v20 = 0.f, v21 = 0.f, v22 = 0.f, v23 = 0.f;   // h = 4*lane + j
    float v3 = 0.f, acc = 0.f;                           // n = lane&15

    const float* xL = lds + XB / 4;
    float xw[12];
    {
        float4 f0 = *(const float4*)(xL + 0);
        float4 f1 = *(const float4*)(xL + 4);
        float4 f2 = *(const float4*)(xL + 8);
        xw[0]=f0.x; xw[1]=f0.y; xw[2]=f0.z; xw[3]=f0.w;
        xw[4]=f1.x; xw[5]=f1.y; xw[6]=f1.z; xw[7]=f1.w;
        xw[8]=f2.x; xw[9]=f2.y; xw[10]=f2.z; xw[11]=f2.w;
    }

    #pragma unroll 1
    for (int cb = 0; cb < TN; cb += 64) {
        // ============ P1: 64-step IF1 scan, masks -> LDS records ============
        #pragma unroll 1
        for (int q = 0; q < 16; ++q) {
            int tb = cb + q * 4;
            float4 fnq = *(const float4*)(xL + tb + 12);
            unsigned ma0 = mbu + (unsigned)(q * 4) * 16u;
            p1_step<0>(lane, ma0,       xw, cwa, cwb, v1a, v1b);
            p1_step<1>(lane, ma0 + 16u, xw, cwa, cwb, v1a, v1b);
            p1_step<2>(lane, ma0 + 32u, xw, cwa, cwb, v1a, v1b);
            p1_step<3>(lane, ma0 + 48u, xw, cwa, cwb, v1a, v1b);
            #pragma unroll
            for (int i = 0; i < 8; ++i) xw[i] = xw[i + 4];
            xw[8] = fnq.x; xw[9] = fnq.y; xw[10] = fnq.z; xw[11] = fnq.w;
        }

        // ============ P1.5a: parallel-t c-list extraction (lane = step) ============
        {
            i32x4 M;
            WAIT0;
            ds_load4i(M, mrd);
            WAIT0;
            u64 lo = ((u64)(u32)M[1] << 32) | (u32)M[0];
            u64 hi = ((u64)(u32)M[3] << 32) | (u32)M[2];
            u32 d0 = 0x80808000u, d1 = 0x80808080u, d2 = 0x80808080u, d3 = 0x80808080u;
            int cnt = 0;
            while (lo | hi) {
                int c = pop_next(lo, hi);
                if (cnt < 15) {
                    int pos = 1 + cnt;
                    int sh = (pos & 3) * 8;
                    u32 ins = ((u32)c) << sh;
                    u32 msk = ~(0xFFu << sh);
                    int dw = pos >> 2;
                    d0 = (dw == 0) ? ((d0 & msk) | ins) : d0;
                    d1 = (dw == 1) ? ((d1 & msk) | ins) : d1;
                    d2 = (dw == 2) ? ((d2 & msk) | ins) : d2;
                    d3 = (dw == 3) ? ((d3 & msk) | ins) : d3;
                }
                ++cnt;
            }
            d0 |= (u32)cnt;
            i32x4 rec = { (int)d0, (int)d1, (int)d2, (int)d3 };
            ds_write4i(r2w, rec);
        }

        // ============ P2: pipelined L2 gather + IF2 scan ============
        {
            WAIT0;
            i32x4 RA, RB;
            f32x4 G0, G1, G2, G3, G4, G5, G6, G7;
            f32x4 H0, H1, H2, H3, H4, H5, H6, H7;
            ds_load4i(RA, r2u);
            WAIT0;
            issue8_from(RA, w1a, G0, G1, G2, G3, G4, G5, G6, G7);
            ds_load4i(RB, r2u + 16u);
            #pragma unroll 1
            for (int it = 0; it < 32; ++it) {
                int t = it * 2;
                WAIT0;   // drains G-gathers(t) + RB (rec t+1)
                issue8_from(RB, w1a, H0, H1, H2, H3, H4, H5, H6, H7);
                consume2(G0, G1, G2, G3, G4, G5, G6, G7, RA, t, lane, w1a, mbu, hbu,
                         v20, v21, v22, v23);
                ds_load4i(RA, r2u + (unsigned)(t + 2) * 16u);
                WAIT0;   // drains H-gathers(t+1) + RA (rec t+2)
                issue8_from(RA, w1a, G0, G1, G2, G3, G4, G5, G6, G7);
                consume2(H0, H1, H2, H3, H4, H5, H6, H7, RB, t + 1, lane, w1a, mbu, hbu,
                         v20, v21, v22, v23);
                ds_load4i(RB, r2u + (unsigned)(t + 3) * 16u);
            }
        }

        // ============ P1.5b: parallel-t (l,sub) extraction ============
        {
            i32x4 HA, HB;
            WAIT0;
            ds_load4i(HA, hrd);
            ds_load4i(HB, hrd + 16u);
            WAIT0;
            u64 h0 = ((u64)(u32)HA[1] << 32) | (u32)HA[0];
            u64 h1 = ((u64)(u32)HA[3] << 32) | (u32)HA[2];
            u64 h2 = ((u64)(u32)HB[1] << 32) | (u32)HB[0];
            u64 h3 = ((u64)(u32)HB[3] << 32) | (u32)HB[2];
            u64 gm = h0 | h1 | h2 | h3;
            u32 d0 = 0x40004000u, d1 = 0x40004000u, d2 = 0x40004000u, d3 = 0x00004000u;
            int c3 = 0;
            while (gm) {
                int l = __builtin_ctzll(gm); gm &= gm - 1ull;
                u32 sub = (u32)((h0 >> l) & 1ull) | ((u32)((h1 >> l) & 1ull) << 1)
                        | ((u32)((h2 >> l) & 1ull) << 2) | ((u32)((h3 >> l) & 1ull) << 3);
                if (c3 < 7) {
                    int lb = 1 + 2 * c3;
                    {   // place l byte
                        int sh = (lb & 3) * 8; u32 ins = ((u32)l) << sh; u32 msk = ~(0xFFu << sh);
                        int dw = lb >> 2;
                        d0 = (dw == 0) ? ((d0 & msk) | ins) : d0;
                        d1 = (dw == 1) ? ((d1 & msk) | ins) : d1;
                        d2 = (dw == 2) ? ((d2 & msk) | ins) : d2;
                        d3 = (dw == 3) ? ((d3 & msk) | ins) : d3;
                    }
                    {   // place sub byte
                        int sb = 2 + 2 * c3;
                        int sh = (sb & 3) * 8; u32 ins = sub << sh; u32 msk = ~(0xFFu << sh);
                        int dw = sb >> 2;
                        d0 = (dw == 0) ? ((d0 & msk) | ins) : d0;
                        d1 = (dw == 1) ? ((d1 & msk) | ins) : d1;
                        d2 = (dw == 2) ? ((d2 & msk) | ins) : d2;
                        d3 = (dw == 3) ? ((d3 & msk) | ins) : d3;
                    }
                }
                ++c3;
            }
            d0 = (d0 & ~0xFFu) | (u32)c3;
            i32x4 rec = { (int)d0, (int)d1, (int)d2, (int)d3 };
            ds_write4i(r3w, rec);
        }

        // ============ P3: pipelined L3 gather + IF3 scan ============
        {
            WAIT0;
            i32x4 SA, SB;
            f32x4 QG0, QG1, QH0, QH1;
            ds_load4i(SA, r3u);
            WAIT0;
            issue2_from(SA, w2a, QG0, QG1);
            ds_load4i(SB, r3u + 16u);
            #pragma unroll 1
            for (int it = 0; it < 32; ++it) {
                int t = it * 2;
                WAIT0;
                issue2_from(SB, w2a, QH0, QH1);
                consume3(QG0, QG1, SA, t, w2a, hbu, v3, acc);
                ds_load4i(SA, r3u + (unsigned)(t + 2) * 16u);
                WAIT0;
                issue2_from(SA, w2a, QG0, QG1);
                consume3(QH0, QH1, SB, t + 1, w2a, hbu, v3, acc);
                ds_load4i(SB, r3u + (unsigned)(t + 3) * 16u);
            }
            WAIT0;   // drain tail pad reads before next chunk overwrites records
        }
    }

    if (lane < 10) out[b * 10 + lane] = acc * (1.0f / 2048.0f);
}

extern "C" void kernel_launch(void* const* d_in, const int* in_sizes, int n_in,
                              void* d_out, int out_size, void* d_ws, size_t ws_size,
                              hipStream_t stream) {
    const float* x     = (const float*)d_in[0];
    const float* convw = (const float*)d_in[1];
    const float* w1    = (const float*)d_in[2];
    const float* w2    = (const float*)d_in[3];
    float* w1T = (float*)d_ws;                 // 131072 B
    float* w2Q = (float*)d_ws + 32768;         //  16640 B

    prep_kernel<<<33, 256, 0, stream>>>(w1, w2, w1T, w2Q);

    const size_t ldsz = 162176;   // bytes
    (void)hipFuncSetAttribute(reinterpret_cast<const void*>(snn_main),
                              hipFuncAttributeMaxDynamicSharedMemorySize, (int)ldsz);
    snn_main<<<128, 256, ldsz, stream>>>(x, convw, w1T, w2Q, (float*)d_out);
}